// Round 2
// baseline (3757.173 us; speedup 1.0000x reference)
//
#include <hip/hip_runtime.h>

#define N_NODES 100000
#define N_EDGES 1600000
#define E_TOT   1700000   // edges + self loops
#define HEADS   8
#define CH      32
#define F       256       // HEADS*CH

static __device__ __forceinline__ float lrelu(float v, float s) { return fmaxf(v, s * v); }

static __device__ __forceinline__ unsigned short f2bf(float f) {
    unsigned u = __float_as_uint(f);
    u += 0x7FFFu + ((u >> 16) & 1u);      // round-to-nearest-even
    return (unsigned short)(u >> 16);
}
static __device__ __forceinline__ float bf2f(unsigned short u) {
    return __uint_as_float(((unsigned)u) << 16);
}

// ---------------- xl = x @ Wl (f32), xr = x @ Wr (bf16)  ([N,32] @ [32,256]) ----------------
__global__ __launch_bounds__(256) void k_gemm(
    const float* __restrict__ x, const float* __restrict__ Wl,
    const float* __restrict__ Wr, float* __restrict__ xl, unsigned short* __restrict__ xr)
{
    __shared__ float xs[64 * CH];
    const int t = threadIdx.x;
    float wl[CH], wr[CH];
#pragma unroll
    for (int k = 0; k < CH; ++k) {
        wl[k] = Wl[k * F + t];     // column t, coalesced across threads
        wr[k] = Wr[k * F + t];
    }
    for (int r0 = blockIdx.x * 64; r0 < N_NODES; r0 += gridDim.x * 64) {
        const int rows = min(64, N_NODES - r0);
        __syncthreads();
        for (int i = t; i < rows * CH; i += 256) xs[i] = x[(size_t)r0 * CH + i];
        __syncthreads();
        for (int r = 0; r < rows; ++r) {
            float al = 0.f, ar = 0.f;
#pragma unroll
            for (int k = 0; k < CH; ++k) {
                const float xv = xs[r * CH + k];   // LDS broadcast
                al = fmaf(xv, wl[k], al);
                ar = fmaf(xv, wr[k], ar);
            }
            xl[(size_t)(r0 + r) * F + t] = al;
            xr[(size_t)(r0 + r) * F + t] = f2bf(ar);
        }
    }
}

// ---------------- edge pass 1: denom[dst,h] += exp(logit) ----------------
// one wave per edge; lane l handles channels 4l..4l+3 of head l>>3
__global__ __launch_bounds__(256) void k_edge_p(
    const int* __restrict__ ei, const float* __restrict__ xl,
    const unsigned short* __restrict__ xr, const float* __restrict__ att,
    float* __restrict__ denom)
{
    const int lane = threadIdx.x & 63;
    const int wid  = (blockIdx.x * blockDim.x + threadIdx.x) >> 6;
    const int nw   = (gridDim.x * blockDim.x) >> 6;
    const float4 a4 = ((const float4*)att)[lane];
    for (int e = wid; e < E_TOT; e += nw) {
        int src, dst;
        if (e < N_EDGES) { src = ei[e]; dst = ei[N_EDGES + e]; }
        else             { src = dst = e - N_EDGES; }
        const float4  vl = ((const float4*)(xl + (size_t)src * F))[lane];
        const ushort4 vr = ((const ushort4*)(xr + (size_t)dst * F))[lane];
        float s = lrelu(vl.x + bf2f(vr.x), 0.2f) * a4.x
                + lrelu(vl.y + bf2f(vr.y), 0.2f) * a4.y
                + lrelu(vl.z + bf2f(vr.z), 0.2f) * a4.z
                + lrelu(vl.w + bf2f(vr.w), 0.2f) * a4.w;
        s += __shfl_xor(s, 1);
        s += __shfl_xor(s, 2);
        s += __shfl_xor(s, 4);
        if ((lane & 7) == 0)
            atomicAdd(&denom[(size_t)dst * 8 + (lane >> 3)], __expf(s));
    }
}

// ---------------- edge pass 2: recompute logit; accum[dst,c] += (1/8)Σ_h alpha·xl[src,h,c] ----------------
__global__ __launch_bounds__(256) void k_edge_acc(
    const int* __restrict__ ei, const float* __restrict__ xl,
    const unsigned short* __restrict__ xr, const float* __restrict__ att,
    const float* __restrict__ denom, float* __restrict__ accum)
{
    const int lane = threadIdx.x & 63;
    const int wid  = (blockIdx.x * blockDim.x + threadIdx.x) >> 6;
    const int nw   = (gridDim.x * blockDim.x) >> 6;
    const float4 a4 = ((const float4*)att)[lane];
    for (int e = wid; e < E_TOT; e += nw) {
        int src, dst;
        if (e < N_EDGES) { src = ei[e]; dst = ei[N_EDGES + e]; }
        else             { src = dst = e - N_EDGES; }
        const float4  vl = ((const float4*)(xl + (size_t)src * F))[lane];
        const ushort4 vr = ((const ushort4*)(xr + (size_t)dst * F))[lane];
        float s = lrelu(vl.x + bf2f(vr.x), 0.2f) * a4.x
                + lrelu(vl.y + bf2f(vr.y), 0.2f) * a4.y
                + lrelu(vl.z + bf2f(vr.z), 0.2f) * a4.z
                + lrelu(vl.w + bf2f(vr.w), 0.2f) * a4.w;
        s += __shfl_xor(s, 1);
        s += __shfl_xor(s, 2);
        s += __shfl_xor(s, 4);
        const float alpha = __expf(s) / denom[(size_t)dst * 8 + (lane >> 3)];
        float c0 = alpha * vl.x, c1 = alpha * vl.y, c2 = alpha * vl.z, c3 = alpha * vl.w;
#pragma unroll
        for (int off = 8; off <= 32; off <<= 1) {   // sum the 8 heads
            c0 += __shfl_xor(c0, off);
            c1 += __shfl_xor(c1, off);
            c2 += __shfl_xor(c2, off);
            c3 += __shfl_xor(c3, off);
        }
        if (lane < 8) {
            float* base = accum + (size_t)dst * CH + 4 * lane;
            atomicAdd(base + 0, 0.125f * c0);
            atomicAdd(base + 1, 0.125f * c1);
            atomicAdd(base + 2, 0.125f * c2);
            atomicAdd(base + 3, 0.125f * c3);
        }
    }
}

// ---------------- post: y = [lrelu](accum+bias) + x; batch stats ----------------
template <int MODE>   // 0: leaky_relu 0.01 + residual, 1: residual only
__global__ __launch_bounds__(256) void k_post(
    float* __restrict__ y, const float* __restrict__ x,
    const float* __restrict__ bias, float* __restrict__ stats)
{
    __shared__ float s1[256], s2[256];
    const int t = threadIdx.x;
    const int c = t & 31;
    const float b = bias[c];
    float ls = 0.f, lq = 0.f;
    for (int i = blockIdx.x * 256 + t; i < N_NODES * CH; i += gridDim.x * 256) {
        float v = y[i] + b;
        if (MODE == 0) v = lrelu(v, 0.01f);
        v += x[i];
        y[i] = v;
        ls += v;
        lq = fmaf(v, v, lq);
    }
    s1[t] = ls; s2[t] = lq;
    __syncthreads();
    if (t < 32) {
        for (int j = 1; j < 8; ++j) { ls += s1[t + 32 * j]; lq += s2[t + 32 * j]; }
        atomicAdd(&stats[c], ls);
        atomicAdd(&stats[32 + c], lq);
    }
}

// ---------------- batchnorm normalize ----------------
__global__ __launch_bounds__(256) void k_bn(
    const float* __restrict__ y, const float* __restrict__ stats,
    const float* __restrict__ g, const float* __restrict__ be,
    float* __restrict__ xo)
{
    const int t = threadIdx.x;
    const int c = t & 31;
    const float mu  = stats[c] * (1.f / N_NODES);
    const float var = stats[32 + c] * (1.f / N_NODES) - mu * mu;
    const float sc  = rsqrtf(var + 1e-5f) * g[c];
    const float sh  = be[c] - mu * sc;
    for (int i = blockIdx.x * 256 + t; i < N_NODES * CH; i += gridDim.x * 256)
        xo[i] = fmaf(y[i], sc, sh);
}

extern "C" void kernel_launch(void* const* d_in, const int* in_sizes, int n_in,
                              void* d_out, int out_size, void* d_ws, size_t ws_size,
                              hipStream_t stream)
{
    const float* x0 = (const float*)d_in[0];
    const int*   ei = (const int*)d_in[1];
    // d_in[2] = edge_attr (unused by reference)

    char* ws = (char*)d_ws;
    float*          xl    = (float*)ws;                              // N*256 f32   102.4 MB
    unsigned short* xr    = (unsigned short*)(xl + (size_t)N_NODES * F); // N*256 bf16  51.2 MB
    float*          accum = (float*)(xr + (size_t)N_NODES * F);      // N*32  f32   12.8 MB
    float*          denom = accum + (size_t)N_NODES * CH;            // N*8   f32    3.2 MB
    float*          stats = denom + (size_t)N_NODES * 8;             // 64    f32
    float*          xbuf  = stats + 64;                              // N*32  f32   12.8 MB
    const size_t needed = (size_t)((char*)(xbuf + (size_t)N_NODES * CH) - ws);
    if (ws_size < needed) return;   // too little scratch: fail validation cleanly, don't fault

    const size_t zero_bytes = ((size_t)N_NODES * CH + (size_t)N_NODES * 8 + 64) * sizeof(float);

    const float* xcur = x0;
    for (int L = 0; L < 3; ++L) {
        const float* Wl  = (const float*)d_in[3 + 6 * L + 0];
        const float* Wr  = (const float*)d_in[3 + 6 * L + 1];
        const float* att = (const float*)d_in[3 + 6 * L + 2];
        const float* b   = (const float*)d_in[3 + 6 * L + 3];
        const float* g   = (const float*)d_in[3 + 6 * L + 4];
        const float* be  = (const float*)d_in[3 + 6 * L + 5];

        hipMemsetAsync(accum, 0, zero_bytes, stream);
        k_gemm<<<1563, 256, 0, stream>>>(xcur, Wl, Wr, xl, xr);
        k_edge_p<<<2048, 256, 0, stream>>>(ei, xl, xr, att, denom);
        k_edge_acc<<<2048, 256, 0, stream>>>(ei, xl, xr, att, denom, accum);
        float* xo = (L == 2) ? (float*)d_out : xbuf;
        if (L < 2) k_post<0><<<1024, 256, 0, stream>>>(accum, xcur, b, stats);
        else       k_post<1><<<1024, 256, 0, stream>>>(accum, xcur, b, stats);
        k_bn<<<2048, 256, 0, stream>>>(accum, stats, g, be, xo);
        xcur = xbuf;
    }
    (void)in_sizes; (void)n_in; (void)out_size;
}

// Round 3
// 1315.288 us; speedup vs baseline: 2.8565x; 2.8565x over previous
//
#include <hip/hip_runtime.h>

#define N_NODES 100000
#define N_EDGES 1600000
#define E_TOT   1700000   // edges + self loops
#define HEADS   8
#define CH      32
#define F       256       // HEADS*CH
#define NCHUNK  ((N_NODES + 255) / 256)   // 391

static __device__ __forceinline__ float lrelu(float v, float s) { return fmaxf(v, s * v); }

static __device__ __forceinline__ unsigned short f2bf(float f) {
    unsigned u = __float_as_uint(f);
    u += 0x7FFFu + ((u >> 16) & 1u);      // round-to-nearest-even
    return (unsigned short)(u >> 16);
}
static __device__ __forceinline__ float bf2f(unsigned short u) {
    return __uint_as_float(((unsigned)u) << 16);
}

// ======================= CSR build (once per call) =======================
__global__ __launch_bounds__(256) void k_deg_init(int* __restrict__ cnt) {
    const int i = blockIdx.x * 256 + threadIdx.x;
    if (i < N_NODES) cnt[i] = 1;          // self loop
}

__global__ __launch_bounds__(256) void k_hist(const int* __restrict__ ei, int* __restrict__ cnt) {
    for (int e = blockIdx.x * 256 + threadIdx.x; e < N_EDGES; e += gridDim.x * 256)
        atomicAdd(&cnt[ei[N_EDGES + e]], 1);
}

// exclusive scan within 256-chunk; chunk totals to csum
__global__ __launch_bounds__(256) void k_scan_chunk(
    const int* __restrict__ cnt, int* __restrict__ row_start, int* __restrict__ csum)
{
    __shared__ int s[256];
    const int t = threadIdx.x;
    const int i = blockIdx.x * 256 + t;
    const int v = (i < N_NODES) ? cnt[i] : 0;
    s[t] = v;
    __syncthreads();
    for (int off = 1; off < 256; off <<= 1) {
        const int y = (t >= off) ? s[t - off] : 0;
        __syncthreads();
        s[t] += y;
        __syncthreads();
    }
    if (i < N_NODES) row_start[i] = s[t] - v;   // exclusive
    if (t == 255) csum[blockIdx.x] = s[t];
}

// exclusive scan of the NCHUNK (=391) chunk totals, one block of 512
__global__ __launch_bounds__(512) void k_scan_top(int* __restrict__ csum) {
    __shared__ int s[512];
    const int t = threadIdx.x;
    const int v = (t < NCHUNK) ? csum[t] : 0;
    s[t] = v;
    __syncthreads();
    for (int off = 1; off < 512; off <<= 1) {
        const int y = (t >= off) ? s[t - off] : 0;
        __syncthreads();
        s[t] += y;
        __syncthreads();
    }
    if (t < NCHUNK) csum[t] = s[t] - v;         // exclusive
}

// finalize row_start, init cursor (skipping the self-loop slot), place self loop
__global__ __launch_bounds__(256) void k_fill_init(
    int* __restrict__ row_start, const int* __restrict__ csum,
    int* __restrict__ cursor, int* __restrict__ csr_src)
{
    const int i = blockIdx.x * 256 + threadIdx.x;
    if (i >= N_NODES) return;
    const int rs = row_start[i] + csum[i >> 8];
    row_start[i] = rs;
    cursor[i] = rs + 1;
    csr_src[rs] = i;                            // self loop first
}

__global__ __launch_bounds__(256) void k_fill(
    const int* __restrict__ ei, int* __restrict__ cursor, int* __restrict__ csr_src)
{
    for (int e = blockIdx.x * 256 + threadIdx.x; e < N_EDGES; e += gridDim.x * 256) {
        const int pos = atomicAdd(&cursor[ei[N_EDGES + e]], 1);
        csr_src[pos] = ei[e];
    }
}
// after k_fill: cursor[i] == row_end[i]

// ============== xl = x @ Wl (f32), xr = x @ Wr (bf16)  ([N,32]@[32,256]) ==============
__global__ __launch_bounds__(256) void k_gemm(
    const float* __restrict__ x, const float* __restrict__ Wl,
    const float* __restrict__ Wr, float* __restrict__ xl, unsigned short* __restrict__ xr)
{
    __shared__ float xs[64 * CH];
    const int t = threadIdx.x;
    float wl[CH], wr[CH];
#pragma unroll
    for (int k = 0; k < CH; ++k) {
        wl[k] = Wl[k * F + t];
        wr[k] = Wr[k * F + t];
    }
    for (int r0 = blockIdx.x * 64; r0 < N_NODES; r0 += gridDim.x * 64) {
        const int rows = min(64, N_NODES - r0);
        __syncthreads();
        for (int i = t; i < rows * CH; i += 256) xs[i] = x[(size_t)r0 * CH + i];
        __syncthreads();
        for (int r = 0; r < rows; ++r) {
            float al = 0.f, ar = 0.f;
#pragma unroll
            for (int k = 0; k < CH; ++k) {
                const float xv = xs[r * CH + k];
                al = fmaf(xv, wl[k], al);
                ar = fmaf(xv, wr[k], ar);
            }
            xl[(size_t)(r0 + r) * F + t] = al;
            xr[(size_t)(r0 + r) * F + t] = f2bf(ar);
        }
    }
}

// ============== single-pass GATv2 aggregation: one wave per dst node ==============
// lane l: head l>>3, channels 4*(l&7)..+3
__global__ __launch_bounds__(256) void k_agg(
    const int* __restrict__ row_start, const int* __restrict__ row_end,
    const int* __restrict__ csr_src, const float* __restrict__ xl,
    const unsigned short* __restrict__ xr, const float* __restrict__ att,
    float* __restrict__ accum)
{
    const int lane = threadIdx.x & 63;
    const int wid  = (blockIdx.x * blockDim.x + threadIdx.x) >> 6;
    const int nw   = (gridDim.x * blockDim.x) >> 6;
    const float4 a4 = ((const float4*)att)[lane];
    for (int n = wid; n < N_NODES; n += nw) {
        const ushort4 vru = ((const ushort4*)(xr + (size_t)n * F))[lane];
        const float rx = bf2f(vru.x), ry = bf2f(vru.y), rz = bf2f(vru.z), rw = bf2f(vru.w);
        float c0 = 0.f, c1 = 0.f, c2 = 0.f, c3 = 0.f, den = 0.f;
        const int e0 = row_start[n], e1 = row_end[n];
        for (int e = e0; e < e1; ++e) {
            const int src = csr_src[e];
            const float4 vl = ((const float4*)(xl + (size_t)src * F))[lane];
            float s = lrelu(vl.x + rx, 0.2f) * a4.x
                    + lrelu(vl.y + ry, 0.2f) * a4.y
                    + lrelu(vl.z + rz, 0.2f) * a4.z
                    + lrelu(vl.w + rw, 0.2f) * a4.w;
            s += __shfl_xor(s, 1);
            s += __shfl_xor(s, 2);
            s += __shfl_xor(s, 4);            // all 8 lanes of the head group hold the logit
            const float pv = __expf(s);
            den += pv;
            c0 = fmaf(pv, vl.x, c0);
            c1 = fmaf(pv, vl.y, c1);
            c2 = fmaf(pv, vl.z, c2);
            c3 = fmaf(pv, vl.w, c3);
        }
        const float inv = 0.125f / den;       // alpha-normalize + head-mean
        c0 *= inv; c1 *= inv; c2 *= inv; c3 *= inv;
#pragma unroll
        for (int off = 8; off <= 32; off <<= 1) {   // sum the 8 heads
            c0 += __shfl_xor(c0, off);
            c1 += __shfl_xor(c1, off);
            c2 += __shfl_xor(c2, off);
            c3 += __shfl_xor(c3, off);
        }
        if (lane < 8)
            ((float4*)(accum + (size_t)n * CH))[lane] = make_float4(c0, c1, c2, c3);
    }
}

// ============== post: y = [lrelu](accum+bias) + x; batch stats ==============
template <int MODE>   // 0: leaky_relu 0.01 + residual, 1: residual only
__global__ __launch_bounds__(256) void k_post(
    float* __restrict__ y, const float* __restrict__ x,
    const float* __restrict__ bias, float* __restrict__ stats)
{
    __shared__ float s1[256], s2[256];
    const int t = threadIdx.x;
    const int c = t & 31;
    const float b = bias[c];
    float ls = 0.f, lq = 0.f;
    for (int i = blockIdx.x * 256 + t; i < N_NODES * CH; i += gridDim.x * 256) {
        float v = y[i] + b;
        if (MODE == 0) v = lrelu(v, 0.01f);
        v += x[i];
        y[i] = v;
        ls += v;
        lq = fmaf(v, v, lq);
    }
    s1[t] = ls; s2[t] = lq;
    __syncthreads();
    if (t < 32) {
        for (int j = 1; j < 8; ++j) { ls += s1[t + 32 * j]; lq += s2[t + 32 * j]; }
        atomicAdd(&stats[c], ls);
        atomicAdd(&stats[32 + c], lq);
    }
}

// ============== batchnorm normalize ==============
__global__ __launch_bounds__(256) void k_bn(
    const float* __restrict__ y, const float* __restrict__ stats,
    const float* __restrict__ g, const float* __restrict__ be,
    float* __restrict__ xo)
{
    const int t = threadIdx.x;
    const int c = t & 31;
    const float mu  = stats[c] * (1.f / N_NODES);
    const float var = stats[32 + c] * (1.f / N_NODES) - mu * mu;
    const float sc  = rsqrtf(var + 1e-5f) * g[c];
    const float sh  = be[c] - mu * sc;
    for (int i = blockIdx.x * 256 + t; i < N_NODES * CH; i += gridDim.x * 256)
        xo[i] = fmaf(y[i], sc, sh);
}

extern "C" void kernel_launch(void* const* d_in, const int* in_sizes, int n_in,
                              void* d_out, int out_size, void* d_ws, size_t ws_size,
                              hipStream_t stream)
{
    const float* x0 = (const float*)d_in[0];
    const int*   ei = (const int*)d_in[1];

    char* ws = (char*)d_ws;
    float*          xl    = (float*)ws;                                   // N*256 f32  102.4 MB
    unsigned short* xr    = (unsigned short*)(xl + (size_t)N_NODES * F);  // N*256 bf16  51.2 MB
    float*          accum = (float*)(xr + (size_t)N_NODES * F);           // N*32  f32   12.8 MB
    float*          stats = accum + (size_t)N_NODES * CH;                 // 64
    int*            cnt   = (int*)(stats + 64);                           // N  (reused as cursor/row_end)
    int*            rowst = cnt + N_NODES;                                // N
    int*            csum  = rowst + N_NODES;                              // NCHUNK
    int*            csr   = csum + NCHUNK;                                // E_TOT  6.8 MB
    const size_t needed = (size_t)((char*)(csr + E_TOT) - ws);            // ~174 MB
    if (ws_size < needed) return;

    // ---- CSR build (identical for all 3 layers) ----
    k_deg_init <<<NCHUNK, 256, 0, stream>>>(cnt);
    k_hist     <<<1024,   256, 0, stream>>>(ei, cnt);
    k_scan_chunk<<<NCHUNK, 256, 0, stream>>>(cnt, rowst, csum);
    k_scan_top <<<1,      512, 0, stream>>>(csum);
    k_fill_init<<<NCHUNK, 256, 0, stream>>>(rowst, csum, cnt, csr);
    k_fill     <<<1024,   256, 0, stream>>>(ei, cnt, csr);

    const float* xcur = x0;
    for (int L = 0; L < 3; ++L) {
        const float* Wl  = (const float*)d_in[3 + 6 * L + 0];
        const float* Wr  = (const float*)d_in[3 + 6 * L + 1];
        const float* att = (const float*)d_in[3 + 6 * L + 2];
        const float* b   = (const float*)d_in[3 + 6 * L + 3];
        const float* g   = (const float*)d_in[3 + 6 * L + 4];
        const float* be  = (const float*)d_in[3 + 6 * L + 5];

        hipMemsetAsync(stats, 0, 64 * sizeof(float), stream);
        k_gemm<<<1563, 256, 0, stream>>>(xcur, Wl, Wr, xl, xr);
        k_agg <<<2048, 256, 0, stream>>>(rowst, cnt, csr, xl, xr, att, accum);
        if (L < 2) k_post<0><<<1024, 256, 0, stream>>>(accum, xcur, b, stats);
        else       k_post<1><<<1024, 256, 0, stream>>>(accum, xcur, b, stats);
        k_bn<<<2048, 256, 0, stream>>>(accum, stats, g, be, (float*)d_out);
        xcur = (const float*)d_out;
    }
    (void)in_sizes; (void)n_in; (void)out_size;
}

// Round 4
// 1147.341 us; speedup vs baseline: 3.2747x; 1.1464x over previous
//
#include <hip/hip_runtime.h>

#define N_NODES 100000
#define N_EDGES 1600000
#define E_TOT   1700000   // edges + self loops
#define HEADS   8
#define CH      32
#define F       256       // HEADS*CH
#define NCHUNK  ((N_NODES + 255) / 256)   // 391

static __device__ __forceinline__ float lrelu(float v, float s) { return fmaxf(v, s * v); }

static __device__ __forceinline__ unsigned short f2bf(float f) {
    unsigned u = __float_as_uint(f);
    u += 0x7FFFu + ((u >> 16) & 1u);      // round-to-nearest-even
    return (unsigned short)(u >> 16);
}
static __device__ __forceinline__ float bf2f(unsigned short u) {
    return __uint_as_float(((unsigned)u) << 16);
}

// ======================= CSR build (once per call) =======================
__global__ __launch_bounds__(256) void k_deg_init(int* __restrict__ cnt) {
    const int i = blockIdx.x * 256 + threadIdx.x;
    if (i < N_NODES) cnt[i] = 1;          // self loop
}

__global__ __launch_bounds__(256) void k_hist(const int* __restrict__ ei, int* __restrict__ cnt) {
    for (int e = blockIdx.x * 256 + threadIdx.x; e < N_EDGES; e += gridDim.x * 256)
        atomicAdd(&cnt[ei[N_EDGES + e]], 1);
}

// exclusive scan within 256-chunk; chunk totals to csum
__global__ __launch_bounds__(256) void k_scan_chunk(
    const int* __restrict__ cnt, int* __restrict__ row_start, int* __restrict__ csum)
{
    __shared__ int s[256];
    const int t = threadIdx.x;
    const int i = blockIdx.x * 256 + t;
    const int v = (i < N_NODES) ? cnt[i] : 0;
    s[t] = v;
    __syncthreads();
    for (int off = 1; off < 256; off <<= 1) {
        const int y = (t >= off) ? s[t - off] : 0;
        __syncthreads();
        s[t] += y;
        __syncthreads();
    }
    if (i < N_NODES) row_start[i] = s[t] - v;   // exclusive
    if (t == 255) csum[blockIdx.x] = s[t];
}

// exclusive scan of the NCHUNK (=391) chunk totals, one block of 512
__global__ __launch_bounds__(512) void k_scan_top(int* __restrict__ csum) {
    __shared__ int s[512];
    const int t = threadIdx.x;
    const int v = (t < NCHUNK) ? csum[t] : 0;
    s[t] = v;
    __syncthreads();
    for (int off = 1; off < 512; off <<= 1) {
        const int y = (t >= off) ? s[t - off] : 0;
        __syncthreads();
        s[t] += y;
        __syncthreads();
    }
    if (t < NCHUNK) csum[t] = s[t] - v;         // exclusive
}

// finalize row_start, init cursor (skipping the self-loop slot), place self loop
__global__ __launch_bounds__(256) void k_fill_init(
    int* __restrict__ row_start, const int* __restrict__ csum,
    int* __restrict__ cursor, int* __restrict__ csr_src)
{
    const int i = blockIdx.x * 256 + threadIdx.x;
    if (i >= N_NODES) return;
    const int rs = row_start[i] + csum[i >> 8];
    row_start[i] = rs;
    cursor[i] = rs + 1;
    csr_src[rs] = i;                            // self loop first
}

__global__ __launch_bounds__(256) void k_fill(
    const int* __restrict__ ei, int* __restrict__ cursor, int* __restrict__ csr_src)
{
    for (int e = blockIdx.x * 256 + threadIdx.x; e < N_EDGES; e += gridDim.x * 256) {
        const int pos = atomicAdd(&cursor[ei[N_EDGES + e]], 1);
        csr_src[pos] = ei[e];
    }
}
// after k_fill: cursor[i] == row_end[i]

// ============== xl = x @ Wl (bf16), xr = x @ Wr (bf16)  ([N,32]@[32,256]) ==============
__global__ __launch_bounds__(256) void k_gemm(
    const float* __restrict__ x, const float* __restrict__ Wl,
    const float* __restrict__ Wr, unsigned short* __restrict__ xl, unsigned short* __restrict__ xr)
{
    __shared__ float xs[64 * CH];
    const int t = threadIdx.x;
    float wl[CH], wr[CH];
#pragma unroll
    for (int k = 0; k < CH; ++k) {
        wl[k] = Wl[k * F + t];
        wr[k] = Wr[k * F + t];
    }
    for (int r0 = blockIdx.x * 64; r0 < N_NODES; r0 += gridDim.x * 64) {
        const int rows = min(64, N_NODES - r0);
        __syncthreads();
        for (int i = t; i < rows * CH; i += 256) xs[i] = x[(size_t)r0 * CH + i];
        __syncthreads();
        for (int r = 0; r < rows; ++r) {
            float al = 0.f, ar = 0.f;
#pragma unroll
            for (int k = 0; k < CH; ++k) {
                const float xv = xs[r * CH + k];
                al = fmaf(xv, wl[k], al);
                ar = fmaf(xv, wr[k], ar);
            }
            xl[(size_t)(r0 + r) * F + t] = f2bf(al);
            xr[(size_t)(r0 + r) * F + t] = f2bf(ar);
        }
    }
}

// ============== single-pass GATv2 aggregation: one wave per dst node ==============
// lane l: head l>>3, channels 4*(l&7)..+3
__global__ __launch_bounds__(256) void k_agg(
    const int* __restrict__ row_start, const int* __restrict__ row_end,
    const int* __restrict__ csr_src, const unsigned short* __restrict__ xl,
    const unsigned short* __restrict__ xr, const float* __restrict__ att,
    float* __restrict__ accum)
{
    const int lane = threadIdx.x & 63;
    const int wid  = (blockIdx.x * blockDim.x + threadIdx.x) >> 6;
    const int nw   = (gridDim.x * blockDim.x) >> 6;
    const float4 a4 = ((const float4*)att)[lane];
    for (int n = wid; n < N_NODES; n += nw) {
        const ushort4 vru = ((const ushort4*)(xr + (size_t)n * F))[lane];
        const float rx = bf2f(vru.x), ry = bf2f(vru.y), rz = bf2f(vru.z), rw = bf2f(vru.w);
        float c0 = 0.f, c1 = 0.f, c2 = 0.f, c3 = 0.f, den = 0.f;
        const int e0 = row_start[n], e1 = row_end[n];
        for (int e = e0; e < e1; ++e) {
            const int src = csr_src[e];
            const ushort4 vlu = ((const ushort4*)(xl + (size_t)src * F))[lane];
            const float lx = bf2f(vlu.x), ly = bf2f(vlu.y), lz = bf2f(vlu.z), lw = bf2f(vlu.w);
            float s = lrelu(lx + rx, 0.2f) * a4.x
                    + lrelu(ly + ry, 0.2f) * a4.y
                    + lrelu(lz + rz, 0.2f) * a4.z
                    + lrelu(lw + rw, 0.2f) * a4.w;
            s += __shfl_xor(s, 1);
            s += __shfl_xor(s, 2);
            s += __shfl_xor(s, 4);            // all 8 lanes of the head group hold the logit
            const float pv = __expf(s);
            den += pv;
            c0 = fmaf(pv, lx, c0);
            c1 = fmaf(pv, ly, c1);
            c2 = fmaf(pv, lz, c2);
            c3 = fmaf(pv, lw, c3);
        }
        const float inv = 0.125f / den;       // alpha-normalize + head-mean
        c0 *= inv; c1 *= inv; c2 *= inv; c3 *= inv;
#pragma unroll
        for (int off = 8; off <= 32; off <<= 1) {   // sum the 8 heads
            c0 += __shfl_xor(c0, off);
            c1 += __shfl_xor(c1, off);
            c2 += __shfl_xor(c2, off);
            c3 += __shfl_xor(c3, off);
        }
        if (lane < 8)
            ((float4*)(accum + (size_t)n * CH))[lane] = make_float4(c0, c1, c2, c3);
    }
}

// ============== post: y = [lrelu](accum+bias) + x; batch stats ==============
template <int MODE>   // 0: leaky_relu 0.01 + residual, 1: residual only
__global__ __launch_bounds__(256) void k_post(
    float* __restrict__ y, const float* __restrict__ x,
    const float* __restrict__ bias, float* __restrict__ stats)
{
    __shared__ float s1[256], s2[256];
    const int t = threadIdx.x;
    const int c = t & 31;
    const float b = bias[c];
    float ls = 0.f, lq = 0.f;
    for (int i = blockIdx.x * 256 + t; i < N_NODES * CH; i += gridDim.x * 256) {
        float v = y[i] + b;
        if (MODE == 0) v = lrelu(v, 0.01f);
        v += x[i];
        y[i] = v;
        ls += v;
        lq = fmaf(v, v, lq);
    }
    s1[t] = ls; s2[t] = lq;
    __syncthreads();
    if (t < 32) {
        for (int j = 1; j < 8; ++j) { ls += s1[t + 32 * j]; lq += s2[t + 32 * j]; }
        atomicAdd(&stats[c], ls);
        atomicAdd(&stats[32 + c], lq);
    }
}

// ============== batchnorm normalize ==============
__global__ __launch_bounds__(256) void k_bn(
    const float* __restrict__ y, const float* __restrict__ stats,
    const float* __restrict__ g, const float* __restrict__ be,
    float* __restrict__ xo)
{
    const int t = threadIdx.x;
    const int c = t & 31;
    const float mu  = stats[c] * (1.f / N_NODES);
    const float var = stats[32 + c] * (1.f / N_NODES) - mu * mu;
    const float sc  = rsqrtf(var + 1e-5f) * g[c];
    const float sh  = be[c] - mu * sc;
    for (int i = blockIdx.x * 256 + t; i < N_NODES * CH; i += gridDim.x * 256)
        xo[i] = fmaf(y[i], sc, sh);
}

extern "C" void kernel_launch(void* const* d_in, const int* in_sizes, int n_in,
                              void* d_out, int out_size, void* d_ws, size_t ws_size,
                              hipStream_t stream)
{
    const float* x0 = (const float*)d_in[0];
    const int*   ei = (const int*)d_in[1];

    char* ws = (char*)d_ws;
    unsigned short* xl    = (unsigned short*)ws;                          // N*256 bf16  51.2 MB
    unsigned short* xr    = xl + (size_t)N_NODES * F;                     // N*256 bf16  51.2 MB
    float*          accum = (float*)(xr + (size_t)N_NODES * F);           // N*32  f32   12.8 MB
    float*          stats = accum + (size_t)N_NODES * CH;                 // 64
    int*            cnt   = (int*)(stats + 64);                           // N  (cursor/row_end)
    int*            rowst = cnt + N_NODES;                                // N
    int*            csum  = rowst + N_NODES;                              // NCHUNK
    int*            csr   = csum + NCHUNK;                                // E_TOT  6.8 MB
    const size_t needed = (size_t)((char*)(csr + E_TOT) - ws);            // ~123 MB
    if (ws_size < needed) return;

    // ---- CSR build (identical for all 3 layers) ----
    k_deg_init <<<NCHUNK, 256, 0, stream>>>(cnt);
    k_hist     <<<1024,   256, 0, stream>>>(ei, cnt);
    k_scan_chunk<<<NCHUNK, 256, 0, stream>>>(cnt, rowst, csum);
    k_scan_top <<<1,      512, 0, stream>>>(csum);
    k_fill_init<<<NCHUNK, 256, 0, stream>>>(rowst, csum, cnt, csr);
    k_fill     <<<1024,   256, 0, stream>>>(ei, cnt, csr);

    const float* xcur = x0;
    for (int L = 0; L < 3; ++L) {
        const float* Wl  = (const float*)d_in[3 + 6 * L + 0];
        const float* Wr  = (const float*)d_in[3 + 6 * L + 1];
        const float* att = (const float*)d_in[3 + 6 * L + 2];
        const float* b   = (const float*)d_in[3 + 6 * L + 3];
        const float* g   = (const float*)d_in[3 + 6 * L + 4];
        const float* be  = (const float*)d_in[3 + 6 * L + 5];

        hipMemsetAsync(stats, 0, 64 * sizeof(float), stream);
        k_gemm<<<1563, 256, 0, stream>>>(xcur, Wl, Wr, xl, xr);
        k_agg <<<2048, 256, 0, stream>>>(rowst, cnt, csr, xl, xr, att, accum);
        if (L < 2) k_post<0><<<1024, 256, 0, stream>>>(accum, xcur, b, stats);
        else       k_post<1><<<1024, 256, 0, stream>>>(accum, xcur, b, stats);
        k_bn<<<2048, 256, 0, stream>>>(accum, stats, g, be, (float*)d_out);
        xcur = (const float*)d_out;
    }
    (void)in_sizes; (void)n_in; (void)out_size;
}

// Round 5
// 962.968 us; speedup vs baseline: 3.9017x; 1.1915x over previous
//
#include <hip/hip_runtime.h>

#define N_NODES 100000
#define N_EDGES 1600000
#define E_TOT   1700000   // edges + self loops
#define HEADS   8
#define CH      32
#define F       256       // HEADS*CH
#define NCHUNK  ((N_NODES + 255) / 256)   // 391

static __device__ __forceinline__ float lrelu(float v, float s) { return fmaxf(v, s * v); }

static __device__ __forceinline__ unsigned short f2bf(float f) {
    unsigned u = __float_as_uint(f);
    u += 0x7FFFu + ((u >> 16) & 1u);      // round-to-nearest-even
    return (unsigned short)(u >> 16);
}
static __device__ __forceinline__ float bf2f(unsigned short u) {
    return __uint_as_float(((unsigned)u) << 16);
}

// ======================= CSR build (once per call) =======================
__global__ __launch_bounds__(256) void k_deg_init(int* __restrict__ cnt) {
    const int i = blockIdx.x * 256 + threadIdx.x;
    if (i < N_NODES) cnt[i] = 1;          // self loop
}

__global__ __launch_bounds__(256) void k_hist(const int* __restrict__ ei, int* __restrict__ cnt) {
    for (int e = blockIdx.x * 256 + threadIdx.x; e < N_EDGES; e += gridDim.x * 256)
        atomicAdd(&cnt[ei[N_EDGES + e]], 1);
}

// exclusive scan within 256-chunk; chunk totals to csum
__global__ __launch_bounds__(256) void k_scan_chunk(
    const int* __restrict__ cnt, int* __restrict__ row_start, int* __restrict__ csum)
{
    __shared__ int s[256];
    const int t = threadIdx.x;
    const int i = blockIdx.x * 256 + t;
    const int v = (i < N_NODES) ? cnt[i] : 0;
    s[t] = v;
    __syncthreads();
    for (int off = 1; off < 256; off <<= 1) {
        const int y = (t >= off) ? s[t - off] : 0;
        __syncthreads();
        s[t] += y;
        __syncthreads();
    }
    if (i < N_NODES) row_start[i] = s[t] - v;   // exclusive
    if (t == 255) csum[blockIdx.x] = s[t];
}

// exclusive scan of the NCHUNK (=391) chunk totals, one block of 512
__global__ __launch_bounds__(512) void k_scan_top(int* __restrict__ csum) {
    __shared__ int s[512];
    const int t = threadIdx.x;
    const int v = (t < NCHUNK) ? csum[t] : 0;
    s[t] = v;
    __syncthreads();
    for (int off = 1; off < 512; off <<= 1) {
        const int y = (t >= off) ? s[t - off] : 0;
        __syncthreads();
        s[t] += y;
        __syncthreads();
    }
    if (t < NCHUNK) csum[t] = s[t] - v;         // exclusive
}

// finalize row_start, init cursor (skipping the self-loop slot), place self loop
__global__ __launch_bounds__(256) void k_fill_init(
    int* __restrict__ row_start, const int* __restrict__ csum,
    int* __restrict__ cursor, int* __restrict__ csr_src)
{
    const int i = blockIdx.x * 256 + threadIdx.x;
    if (i >= N_NODES) return;
    const int rs = row_start[i] + csum[i >> 8];
    row_start[i] = rs;
    cursor[i] = rs + 1;
    csr_src[rs] = i;                            // self loop first
}

__global__ __launch_bounds__(256) void k_fill(
    const int* __restrict__ ei, int* __restrict__ cursor, int* __restrict__ csr_src)
{
    for (int e = blockIdx.x * 256 + threadIdx.x; e < N_EDGES; e += gridDim.x * 256) {
        const int pos = atomicAdd(&cursor[ei[N_EDGES + e]], 1);
        csr_src[pos] = ei[e];
    }
}
// after k_fill: cursor[i] == row_end[i]

// ============== xl = x @ Wl (bf16), xr = x @ Wr (bf16)  ([N,32]@[32,256]) ==============
__global__ __launch_bounds__(256) void k_gemm(
    const float* __restrict__ x, const float* __restrict__ Wl,
    const float* __restrict__ Wr, unsigned short* __restrict__ xl, unsigned short* __restrict__ xr)
{
    __shared__ float xs[64 * CH];
    const int t = threadIdx.x;
    float wl[CH], wr[CH];
#pragma unroll
    for (int k = 0; k < CH; ++k) {
        wl[k] = Wl[k * F + t];
        wr[k] = Wr[k * F + t];
    }
    for (int r0 = blockIdx.x * 64; r0 < N_NODES; r0 += gridDim.x * 64) {
        const int rows = min(64, N_NODES - r0);
        __syncthreads();
        for (int i = t; i < rows * CH; i += 256) xs[i] = x[(size_t)r0 * CH + i];
        __syncthreads();
        for (int r = 0; r < rows; ++r) {
            float al = 0.f, ar = 0.f;
#pragma unroll
            for (int k = 0; k < CH; ++k) {
                const float xv = xs[r * CH + k];
                al = fmaf(xv, wl[k], al);
                ar = fmaf(xv, wr[k], ar);
            }
            xl[(size_t)(r0 + r) * F + t] = f2bf(al);
            xr[(size_t)(r0 + r) * F + t] = f2bf(ar);
        }
    }
}

// ============== single-pass GATv2 aggregation: one wave per dst node ==============
// lane l: head l>>3, channels 4*(l&7)..+3
// unroll-by-2: two edges in flight, two independent logit/exp/accum chains
__global__ __launch_bounds__(256) void k_agg(
    const int* __restrict__ row_start, const int* __restrict__ row_end,
    const int* __restrict__ csr_src, const unsigned short* __restrict__ xl,
    const unsigned short* __restrict__ xr, const float* __restrict__ att,
    float* __restrict__ accum)
{
    const int lane = threadIdx.x & 63;
    const int wid  = (blockIdx.x * blockDim.x + threadIdx.x) >> 6;
    const int nw   = (gridDim.x * blockDim.x) >> 6;
    const float4 a4 = ((const float4*)att)[lane];
    const ushort4* __restrict__ xl4 = (const ushort4*)xl;
    for (int n = wid; n < N_NODES; n += nw) {
        const ushort4 vru = ((const ushort4*)(xr + (size_t)n * F))[lane];
        const float rx = bf2f(vru.x), ry = bf2f(vru.y), rz = bf2f(vru.z), rw = bf2f(vru.w);
        float c0a = 0.f, c1a = 0.f, c2a = 0.f, c3a = 0.f, dena = 0.f;
        float c0b = 0.f, c1b = 0.f, c2b = 0.f, c3b = 0.f, denb = 0.f;
        const int e0 = row_start[n], e1 = row_end[n];
        int e = e0;
        for (; e + 1 < e1; e += 2) {
            const unsigned ia = (unsigned)csr_src[e]     * 64u + (unsigned)lane;
            const unsigned ib = (unsigned)csr_src[e + 1] * 64u + (unsigned)lane;
            const ushort4 va = xl4[ia];           // both loads issued before any use:
            const ushort4 vb = xl4[ib];           // two gathers in flight
            const float ax = bf2f(va.x), ay = bf2f(va.y), az = bf2f(va.z), aw = bf2f(va.w);
            const float bx = bf2f(vb.x), by = bf2f(vb.y), bz = bf2f(vb.z), bw = bf2f(vb.w);
            float sA = lrelu(ax + rx, 0.2f) * a4.x
                     + lrelu(ay + ry, 0.2f) * a4.y
                     + lrelu(az + rz, 0.2f) * a4.z
                     + lrelu(aw + rw, 0.2f) * a4.w;
            float sB = lrelu(bx + rx, 0.2f) * a4.x
                     + lrelu(by + ry, 0.2f) * a4.y
                     + lrelu(bz + rz, 0.2f) * a4.z
                     + lrelu(bw + rw, 0.2f) * a4.w;
            sA += __shfl_xor(sA, 1);  sB += __shfl_xor(sB, 1);
            sA += __shfl_xor(sA, 2);  sB += __shfl_xor(sB, 2);
            sA += __shfl_xor(sA, 4);  sB += __shfl_xor(sB, 4);
            const float pA = __expf(sA);
            const float pB = __expf(sB);
            dena += pA;                denb += pB;
            c0a = fmaf(pA, ax, c0a);   c0b = fmaf(pB, bx, c0b);
            c1a = fmaf(pA, ay, c1a);   c1b = fmaf(pB, by, c1b);
            c2a = fmaf(pA, az, c2a);   c2b = fmaf(pB, bz, c2b);
            c3a = fmaf(pA, aw, c3a);   c3b = fmaf(pB, bw, c3b);
        }
        if (e < e1) {                              // remainder edge
            const unsigned ia = (unsigned)csr_src[e] * 64u + (unsigned)lane;
            const ushort4 va = xl4[ia];
            const float ax = bf2f(va.x), ay = bf2f(va.y), az = bf2f(va.z), aw = bf2f(va.w);
            float sA = lrelu(ax + rx, 0.2f) * a4.x
                     + lrelu(ay + ry, 0.2f) * a4.y
                     + lrelu(az + rz, 0.2f) * a4.z
                     + lrelu(aw + rw, 0.2f) * a4.w;
            sA += __shfl_xor(sA, 1);
            sA += __shfl_xor(sA, 2);
            sA += __shfl_xor(sA, 4);
            const float pA = __expf(sA);
            dena += pA;
            c0a = fmaf(pA, ax, c0a);
            c1a = fmaf(pA, ay, c1a);
            c2a = fmaf(pA, az, c2a);
            c3a = fmaf(pA, aw, c3a);
        }
        float c0 = c0a + c0b, c1 = c1a + c1b, c2 = c2a + c2b, c3 = c3a + c3b;
        const float inv = 0.125f / (dena + denb);  // alpha-normalize + head-mean
        c0 *= inv; c1 *= inv; c2 *= inv; c3 *= inv;
#pragma unroll
        for (int off = 8; off <= 32; off <<= 1) {  // sum the 8 heads
            c0 += __shfl_xor(c0, off);
            c1 += __shfl_xor(c1, off);
            c2 += __shfl_xor(c2, off);
            c3 += __shfl_xor(c3, off);
        }
        if (lane < 8)
            ((float4*)(accum + (size_t)n * CH))[lane] = make_float4(c0, c1, c2, c3);
    }
}

// ============== post: y = [lrelu](accum+bias) + x; batch stats ==============
template <int MODE>   // 0: leaky_relu 0.01 + residual, 1: residual only
__global__ __launch_bounds__(256) void k_post(
    float* __restrict__ y, const float* __restrict__ x,
    const float* __restrict__ bias, float* __restrict__ stats)
{
    __shared__ float s1[256], s2[256];
    const int t = threadIdx.x;
    const int c = t & 31;
    const float b = bias[c];
    float ls = 0.f, lq = 0.f;
    for (int i = blockIdx.x * 256 + t; i < N_NODES * CH; i += gridDim.x * 256) {
        float v = y[i] + b;
        if (MODE == 0) v = lrelu(v, 0.01f);
        v += x[i];
        y[i] = v;
        ls += v;
        lq = fmaf(v, v, lq);
    }
    s1[t] = ls; s2[t] = lq;
    __syncthreads();
    if (t < 32) {
        for (int j = 1; j < 8; ++j) { ls += s1[t + 32 * j]; lq += s2[t + 32 * j]; }
        atomicAdd(&stats[c], ls);
        atomicAdd(&stats[32 + c], lq);
    }
}

// ============== batchnorm normalize ==============
__global__ __launch_bounds__(256) void k_bn(
    const float* __restrict__ y, const float* __restrict__ stats,
    const float* __restrict__ g, const float* __restrict__ be,
    float* __restrict__ xo)
{
    const int t = threadIdx.x;
    const int c = t & 31;
    const float mu  = stats[c] * (1.f / N_NODES);
    const float var = stats[32 + c] * (1.f / N_NODES) - mu * mu;
    const float sc  = rsqrtf(var + 1e-5f) * g[c];
    const float sh  = be[c] - mu * sc;
    for (int i = blockIdx.x * 256 + t; i < N_NODES * CH; i += gridDim.x * 256)
        xo[i] = fmaf(y[i], sc, sh);
}

extern "C" void kernel_launch(void* const* d_in, const int* in_sizes, int n_in,
                              void* d_out, int out_size, void* d_ws, size_t ws_size,
                              hipStream_t stream)
{
    const float* x0 = (const float*)d_in[0];
    const int*   ei = (const int*)d_in[1];

    char* ws = (char*)d_ws;
    unsigned short* xl    = (unsigned short*)ws;                          // N*256 bf16  51.2 MB
    unsigned short* xr    = xl + (size_t)N_NODES * F;                     // N*256 bf16  51.2 MB
    float*          accum = (float*)(xr + (size_t)N_NODES * F);           // N*32  f32   12.8 MB
    float*          stats = accum + (size_t)N_NODES * CH;                 // 64
    int*            cnt   = (int*)(stats + 64);                           // N  (cursor/row_end)
    int*            rowst = cnt + N_NODES;                                // N
    int*            csum  = rowst + N_NODES;                              // NCHUNK
    int*            csr   = csum + NCHUNK;                                // E_TOT  6.8 MB
    const size_t needed = (size_t)((char*)(csr + E_TOT) - ws);            // ~123 MB
    if (ws_size < needed) return;

    // ---- CSR build (identical for all 3 layers) ----
    k_deg_init <<<NCHUNK, 256, 0, stream>>>(cnt);
    k_hist     <<<1024,   256, 0, stream>>>(ei, cnt);
    k_scan_chunk<<<NCHUNK, 256, 0, stream>>>(cnt, rowst, csum);
    k_scan_top <<<1,      512, 0, stream>>>(csum);
    k_fill_init<<<NCHUNK, 256, 0, stream>>>(rowst, csum, cnt, csr);
    k_fill     <<<1024,   256, 0, stream>>>(ei, cnt, csr);

    const float* xcur = x0;
    for (int L = 0; L < 3; ++L) {
        const float* Wl  = (const float*)d_in[3 + 6 * L + 0];
        const float* Wr  = (const float*)d_in[3 + 6 * L + 1];
        const float* att = (const float*)d_in[3 + 6 * L + 2];
        const float* b   = (const float*)d_in[3 + 6 * L + 3];
        const float* g   = (const float*)d_in[3 + 6 * L + 4];
        const float* be  = (const float*)d_in[3 + 6 * L + 5];

        hipMemsetAsync(stats, 0, 64 * sizeof(float), stream);
        k_gemm<<<1563, 256, 0, stream>>>(xcur, Wl, Wr, xl, xr);
        k_agg <<<2048, 256, 0, stream>>>(rowst, cnt, csr, xl, xr, att, accum);
        if (L < 2) k_post<0><<<1024, 256, 0, stream>>>(accum, xcur, b, stats);
        else       k_post<1><<<1024, 256, 0, stream>>>(accum, xcur, b, stats);
        k_bn<<<2048, 256, 0, stream>>>(accum, stats, g, be, (float*)d_out);
        xcur = (const float*)d_out;
    }
    (void)in_sizes; (void)n_in; (void)out_size;
}